// Round 10
// baseline (380.299 us; speedup 1.0000x reference)
//
#include <hip/hip_runtime.h>
#include <stdint.h>

#define BATCH 4
#define HH 128
#define WW 128
#define CIN 256
#define CO 512
#define HP 130
#define NPIX (BATCH*HH*WW)          // 65536
#define LOGITS_N (NPIX*6)           // 393216
#define DELTA_BASE (2*LOGITS_N)     // 786432

typedef short bf16x8 __attribute__((ext_vector_type(8)));
typedef unsigned short u16x8 __attribute__((ext_vector_type(8)));
typedef float f32x4 __attribute__((ext_vector_type(4)));
typedef unsigned int u32;

__device__ __forceinline__ unsigned short f2bf(float f) {
    union { float f; unsigned int u; } v; v.f = f;
    return (unsigned short)((v.u + 0x7FFFu + ((v.u >> 16) & 1u)) >> 16);
}

__device__ __forceinline__ void gload16(const unsigned short* g, char* l) {
    __builtin_amdgcn_global_load_lds(
        (const __attribute__((address_space(1))) u32*)g,
        (__attribute__((address_space(3))) u32*)l, 16, 0, 0);
}

// ---- pass 1a: fp32 input -> bf16 with 1-pixel zero halo: [B][130][130][256]
__global__ __launch_bounds__(256) void k_pad_convert(const float* __restrict__ in,
                                                     unsigned short* __restrict__ out) {
    size_t q = (size_t)blockIdx.x*256 + threadIdx.x;     // quad index (4 channels)
    if (q >= (size_t)BATCH*HP*HP*64) return;
    int c4 = ((int)q & 63) * 4;
    int pix = (int)(q >> 6);
    int xx = pix % HP; int t = pix / HP; int yy = t % HP; int b = t / HP;
    ushort4 r = {0, 0, 0, 0};
    if (yy >= 1 && yy <= HH && xx >= 1 && xx <= WW) {
        const float4 v = *(const float4*)(in + (((size_t)(b*HH) + (yy-1))*WW + (xx-1))*CIN + c4);
        r.x = f2bf(v.x); r.y = f2bf(v.y); r.z = f2bf(v.z); r.w = f2bf(v.w);
    }
    *(ushort4*)(out + (size_t)pix*CIN + c4) = r;
}

// ---- pass 1b: w_shared [9][256][512] fp32 -> wT [9][512][256] bf16
__global__ __launch_bounds__(256) void k_wt_convert(const float* __restrict__ w,
                                                    unsigned short* __restrict__ wt) {
    int n = blockIdx.x % CO; int tap = blockIdx.x / CO;
    int c = threadIdx.x;
    wt[((size_t)tap*CO + n)*CIN + c] = f2bf(w[((size_t)tap*CIN + c)*CO + n]);
}

// ==== main: 256x256 tile; A staged via gload_lds (32KB/buf, dbuf); B DIRECT from L2 to
// VGPRs (no LDS). kk-split MFMA (32 kk0 then 32 kk1); kk1 ds_reads hide under kk0 MFMAs.
// 512 thr, 8 waves (2M x 4N). LDS main use: 64KB; epilogue: 87KB (dynamic = 87040).
__global__ __launch_bounds__(512, 2) void k_main8(
    const unsigned short* __restrict__ in_p,   // bf16 padded input
    const unsigned short* __restrict__ wt,     // bf16 wT [9][512][256]
    const float* __restrict__ b_sh,
    const float* __restrict__ w_cls,
    const float* __restrict__ w_dlt,
    float* __restrict__ part)                  // [2][NPIX][18]
{
    extern __shared__ char LDS[];

    const int tid  = threadIdx.x;
    const int lane = tid & 63, wave = tid >> 6;
    const int l15  = lane & 15, l4 = lane >> 4;
    const int wm   = wave >> 2, wn = wave & 3;

    // XCD-contiguous bijective swizzle (512 % 8 == 0)
    const int bid   = ((blockIdx.x & 7) << 6) + (blockIdx.x >> 3);
    const int ntile = bid & 1, mtile = bid >> 1;
    const int n0 = ntile << 8;
    const int b  = mtile >> 6;
    const int y0 = (mtile & 63) * 2;           // tile covers image rows y0, y0+1

    // per-thread A staging offset (inverse XOR on source; linear LDS dest)
    const int rl0 = tid >> 3, pc0 = tid & 7;
    const int kc0 = pc0 ^ (rl0 & 7);
    const int off = rl0*256 + kc0*8;           // elements
    const int t16 = tid*16;                    // LDS dest byte offset

    // A fragment LDS byte offsets (swizzled reads; 2-way bank alias = free)
    int base_a[2];
    #pragma unroll
    for (int kk = 0; kk < 2; kk++) {
        int swz = ((kk*32 + l4*8)*2) ^ ((l15 & 7) << 4);
        base_a[kk] = (wm*128 + l15)*128 + swz;
    }

    // B per-lane global element offset within a (tap,kq,kk) panel:
    // row = n0 + wn*64 + ni*16 + l15, k = kq*64 + kk*32 + l4*8
    const size_t bll = (size_t)(n0 + wn*64 + l15)*256 + l4*8;

    f32x4 acc[8][4];
    const f32x4 zz = {0.f, 0.f, 0.f, 0.f};
    #pragma unroll
    for (int mi = 0; mi < 8; mi++)
        #pragma unroll
        for (int ni = 0; ni < 4; ni++) acc[mi][ni] = zz;

    bf16x8 X[4], Y[4];

    // ---- prologue: stage A(0) (lo halves, then hi halves), then B(0,kk0) -> X
    {
        const unsigned short* gA0 = in_p + ((size_t)(b*HP + y0))*HP*256;
        gload16(gA0 + off,          LDS + t16);            // rows 0-63
        gload16(gA0 + 33280 + off,  LDS + 16384 + t16);    // rows 128-191
        __builtin_amdgcn_sched_barrier(0);
        gload16(gA0 + 16384 + off,  LDS + 8192 + t16);     // rows 64-127
        gload16(gA0 + 49664 + off,  LDS + 24576 + t16);    // rows 192-255
        __builtin_amdgcn_sched_barrier(0);
        const unsigned short* gBX = wt + bll;              // tap0, kq0, kk0
        X[0] = *(const bf16x8*)(gBX);
        X[1] = *(const bf16x8*)(gBX + 4096);
        X[2] = *(const bf16x8*)(gBX + 8192);
        X[3] = *(const bf16x8*)(gBX + 12288);
        __builtin_amdgcn_sched_barrier(0);
    }
    asm volatile("s_waitcnt vmcnt(6)" ::: "memory");       // A-lo(0) landed
    __builtin_amdgcn_sched_barrier(0);
    __builtin_amdgcn_s_barrier();
    __builtin_amdgcn_sched_barrier(0);

#define LOAD_QK(AQ, Q, KK)                                                     \
    AQ[0] = *(const bf16x8*)(bufc + base_a[KK] + (2*(Q))*2048);                \
    AQ[1] = *(const bf16x8*)(bufc + base_a[KK] + (2*(Q)+1)*2048);

#define MFMA_QK(Q, AQ, BREG)                                                   \
    __builtin_amdgcn_s_setprio(1);                                             \
    _Pragma("unroll")                                                          \
    for (int mm = 0; mm < 2; mm++)                                             \
        _Pragma("unroll")                                                      \
        for (int ni = 0; ni < 4; ni++)                                         \
            acc[2*(Q)+mm][ni] = __builtin_amdgcn_mfma_f32_16x16x32_bf16(       \
                AQ[mm], BREG[ni], acc[2*(Q)+mm][ni], 0, 0, 0);                 \
    __builtin_amdgcn_s_setprio(0);

#define STEP_BODY(S, BC, BN)                                                   \
{                                                                              \
    const int s = (S);                                                         \
    const bool more = (s < 35);                                                \
    const int s1 = s + 1;                                                      \
    const int tap1 = s1 >> 2, kq1 = s1 & 3;                                    \
    const int dy1 = (tap1*11) >> 5, dx1 = tap1 - dy1*3;                        \
    const int tap0 = s >> 2, kq0 = s & 3;                                      \
    const unsigned short* gA  = in_p + ((size_t)((b*HP + y0 + dy1)*HP + dx1))*256 + kq1*64; \
    const unsigned short* gBd = wt + bll + (size_t)tap0*131072 + kq0*64 + 32;  \
    const unsigned short* gBn = wt + bll + (size_t)tap1*131072 + kq1*64;       \
    const int cur = s & 1;                                                     \
    const char* bufc = LDS + (cur << 15);                                      \
    char* Ad = LDS + ((cur ^ 1) << 15);                                        \
    bf16x8 a0[2], a1[2], a2[2], a3[2];                                         \
    bf16x8 Bd[4];                                                              \
    LOAD_QK(a0, 0, 0) LOAD_QK(a1, 1, 0)                                        \
    __builtin_amdgcn_sched_barrier(0);                                         \
    if (more) { gload16(gA + off,         Ad + t16);                           \
                gload16(gA + 33280 + off, Ad + 16384 + t16); }                 \
    __builtin_amdgcn_sched_barrier(0);                                         \
    Bd[0] = *(const bf16x8*)(gBd);                                             \
    Bd[1] = *(const bf16x8*)(gBd + 4096);                                      \
    Bd[2] = *(const bf16x8*)(gBd + 8192);                                      \
    Bd[3] = *(const bf16x8*)(gBd + 12288);                                     \
    __builtin_amdgcn_sched_barrier(0);                                         \
    if (more) { gload16(gA + 16384 + off, Ad + 8192 + t16);                    \
                gload16(gA + 49664 + off, Ad + 24576 + t16); }                 \
    __builtin_amdgcn_sched_barrier(0);                                         \
    if (more) { BN[0] = *(const bf16x8*)(gBn);                                 \
                BN[1] = *(const bf16x8*)(gBn + 4096);                          \
                BN[2] = *(const bf16x8*)(gBn + 8192);                          \
                BN[3] = *(const bf16x8*)(gBn + 12288); }                       \
    __builtin_amdgcn_sched_barrier(0);                                         \
    if (more) { asm volatile("s_waitcnt vmcnt(16)" ::: "memory"); }            \
    else      { asm volatile("s_waitcnt vmcnt(8)"  ::: "memory"); }            \
    __builtin_amdgcn_sched_barrier(0);                                         \
    LOAD_QK(a2, 2, 0) LOAD_QK(a3, 3, 0)                                        \
    MFMA_QK(0, a0, BC)                                                         \
    MFMA_QK(1, a1, BC)                                                         \
    MFMA_QK(2, a2, BC)                                                         \
    bf16x8 c0[2], c1[2], c2[2], c3[2];                                         \
    LOAD_QK(c0, 0, 1) LOAD_QK(c1, 1, 1)                                        \
    LOAD_QK(c2, 2, 1) LOAD_QK(c3, 3, 1)                                        \
    MFMA_QK(3, a3, BC)                                                         \
    MFMA_QK(0, c0, Bd)                                                         \
    MFMA_QK(1, c1, Bd)                                                         \
    MFMA_QK(2, c2, Bd)                                                         \
    MFMA_QK(3, c3, Bd)                                                         \
    __builtin_amdgcn_sched_barrier(0);                                         \
    __builtin_amdgcn_s_barrier();                                              \
    __builtin_amdgcn_sched_barrier(0);                                         \
}

    for (int s2 = 0; s2 < 36; s2 += 2) {
        STEP_BODY(s2,     X, Y)
        STEP_BODY(s2 + 1, Y, X)
    }
#undef STEP_BODY
#undef MFMA_QK
#undef LOAD_QK

    // ---- epilogue: bias+ReLU + 1x1-head partial reduction over this block's 256 channels
    float* shf = (float*)LDS;                  // [64 cols][260]
    float* sW  = (float*)(LDS + 66560);        // [256][20]
    for (int j = tid; j < 256*18; j += 512) {
        int c = j / 18, o = j - c*18;
        sW[c*20 + o] = (o < 6) ? w_cls[(size_t)(n0 + c)*6 + o]
                               : w_dlt[(size_t)(n0 + c)*12 + (o - 6)];
    }
    float bsh[4];
    #pragma unroll
    for (int ni = 0; ni < 4; ni++) bsh[ni] = b_sh[n0 + wn*64 + ni*16 + l15];

    float a18[18];
    #pragma unroll
    for (int o = 0; o < 18; o++) a18[o] = 0.f;
    const int rr = tid & 255, chalf = tid >> 8;
    __syncthreads();

    for (int p = 0; p < 4; ++p) {
        if (wn == p) {
            #pragma unroll
            for (int mi = 0; mi < 8; mi++)
                #pragma unroll
                for (int ni = 0; ni < 4; ni++) {
                    int colL = ni*16 + l15;
                    int row0 = wm*128 + mi*16 + l4*4;
                    f32x4 v = acc[mi][ni];
                    f32x4 sv;
                    #pragma unroll
                    for (int r = 0; r < 4; r++) sv[r] = fmaxf(v[r] + bsh[ni], 0.f);
                    *(f32x4*)(shf + colL*260 + row0) = sv;
                }
        }
        __syncthreads();
        #pragma unroll 4
        for (int i = 0; i < 32; i++) {
            int c = chalf*32 + i;
            float v = shf[c*260 + rr];
            const float* wrow = sW + (p*64 + c)*20;
            #pragma unroll
            for (int o = 0; o < 18; o++) a18[o] += v * wrow[o];
        }
        __syncthreads();
    }

    if (chalf == 1) {
        #pragma unroll
        for (int o = 0; o < 18; o++) shf[rr*18 + o] = a18[o];
    }
    __syncthreads();
    if (chalf == 0) {
        float* dst = part + ((size_t)ntile*NPIX + (size_t)mtile*256 + rr)*18;
        #pragma unroll
        for (int o = 0; o < 18; o++) dst[o] = a18[o] + shf[rr*18 + o];
    }
}

// ---- finalize (ws path): sum 2 partials, biases, softmax -> all outputs
__global__ __launch_bounds__(256) void k_finalize_ws(const float* __restrict__ part,
                                                     float* __restrict__ out,
                                                     const float* __restrict__ b_cls,
                                                     const float* __restrict__ b_dlt) {
    int pix = blockIdx.x*256 + threadIdx.x;
    if (pix >= NPIX) return;
    float s[18];
    #pragma unroll
    for (int o = 0; o < 18; o++)
        s[o] = part[(size_t)pix*18 + o] + part[((size_t)NPIX + pix)*18 + o];
    float* lo = out + (size_t)pix*6;
    float* pr = out + (size_t)LOGITS_N + (size_t)pix*6;
    float* dl = out + (size_t)DELTA_BASE + (size_t)pix*12;
    #pragma unroll
    for (int a = 0; a < 3; a++) {
        float l0 = s[a*2]   + b_cls[a*2];
        float l1 = s[a*2+1] + b_cls[a*2+1];
        lo[a*2] = l0; lo[a*2+1] = l1;
        float m = fmaxf(l0, l1);
        float e0 = __expf(l0 - m), e1 = __expf(l1 - m);
        float inv = 1.f / (e0 + e1);
        pr[a*2] = e0*inv; pr[a*2+1] = e1*inv;
    }
    #pragma unroll
    for (int o = 0; o < 12; o++) dl[o] = s[6 + o] + b_dlt[o];
}

// ======== fallback path (no workspace): round-2 proven kernel, atomics ========
__global__ __launch_bounds__(256) void k_main_fb(
    const float* __restrict__ in_f, const float* __restrict__ w_f,
    const float* __restrict__ b_sh, const float* __restrict__ w_cls,
    const float* __restrict__ w_dlt, float* __restrict__ out)
{
    __shared__ float smemf[11008];
    char* smem  = (char*)smemf;
    char* smemB = smem + 16384;
    const int tid = threadIdx.x;
    const int lane = tid & 63, wave = tid >> 6;
    const int l15 = lane & 15, l4 = lane >> 4;
    const int wr = wave >> 1, wc = wave & 1;
    int bid = ((blockIdx.x & 7) << 8) + (blockIdx.x >> 3);
    const int ntile = bid & 3, mtile = bid >> 2;
    const int n0 = ntile << 7;
    const int b = mtile >> 7, y = mtile & 127;
    int aoff[4][2], boff[4][2];
    #pragma unroll
    for (int mi = 0; mi < 4; mi++) {
        int rowA = wr*64 + mi*16 + l15;
        int rowB = wc*64 + mi*16 + l15;
        #pragma unroll
        for (int kk = 0; kk < 2; kk++) {
            int kb = (kk*32 + l4*8) * 2;
            aoff[mi][kk] = rowA*128 + (kb ^ ((rowA & 7) << 4));
            boff[mi][kk] = rowB*128 + (kb ^ ((rowB & 7) << 4));
        }
    }
    f32x4 acc[4][4];
    const f32x4 zz = {0.f, 0.f, 0.f, 0.f};
    #pragma unroll
    for (int mi = 0; mi < 4; mi++)
        #pragma unroll
        for (int ni = 0; ni < 4; ni++) acc[mi][ni] = zz;
    for (int s = 0; s < 36; s++) {
        int tap = s >> 2, kq = s & 3;
        int dy = tap / 3, dx = tap - dy*3;
        const int c0 = kq * 64;
        const int yy = y + dy - 1;
        const bool yok = (yy >= 0) && (yy < HH);
        #pragma unroll
        for (int i = 0; i < 4; i++) {
            int ci = i*256 + tid;
            int row = ci >> 3, pc = ci & 7;
            int kc = pc ^ (row & 7);
            int xx = row + dx - 1;
            u16x8 a;
            if (yok && xx >= 0 && xx < WW) {
                const float* sp = in_f + (((size_t)(b*HH) + yy)*WW + xx)*CIN + c0 + kc*8;
                #pragma unroll
                for (int j = 0; j < 8; j++) a[j] = (short)f2bf(sp[j]);
            } else {
                #pragma unroll
                for (int j = 0; j < 8; j++) a[j] = 0;
            }
            *(u16x8*)(smem + ci*16) = a;
            const float* wsrc = w_f + ((size_t)(tap*CIN + c0 + kc*8))*CO + n0 + row;
            u16x8 bb;
            #pragma unroll
            for (int j = 0; j < 8; j++) bb[j] = (short)f2bf(wsrc[(size_t)j*CO]);
            *(u16x8*)(smemB + ci*16) = bb;
        }
        __syncthreads();
        #pragma unroll
        for (int kk = 0; kk < 2; kk++) {
            bf16x8 av[4], bv[4];
            #pragma unroll
            for (int mi = 0; mi < 4; mi++) av[mi] = *(const bf16x8*)(smem  + aoff[mi][kk]);
            #pragma unroll
            for (int ni = 0; ni < 4; ni++) bv[ni] = *(const bf16x8*)(smemB + boff[ni][kk]);
            #pragma unroll
            for (int mi = 0; mi < 4; mi++)
                #pragma unroll
                for (int ni = 0; ni < 4; ni++)
                    acc[mi][ni] = __builtin_amdgcn_mfma_f32_16x16x32_bf16(
                        av[mi], bv[ni], acc[mi][ni], 0, 0, 0);
        }
        __syncthreads();
    }
    float* shf = smemf;
    float* sW  = smemf + 8448;
    for (int j = tid; j < 128*18; j += 256) {
        int c = j / 18, o = j - c*18;
        sW[c*20 + o] = (o < 6) ? w_cls[(size_t)(n0 + c)*6 + o]
                               : w_dlt[(size_t)(n0 + c)*12 + (o - 6)];
    }
    float bsh[4];
    #pragma unroll
    for (int ni = 0; ni < 4; ni++) bsh[ni] = b_sh[n0 + wc*64 + ni*16 + l15];
    float a18[18];
    #pragma unroll
    for (int o = 0; o < 18; o++) a18[o] = 0.f;
    const int rr = tid & 127, chalf = tid >> 7;
    #pragma unroll
    for (int pass = 0; pass < 2; pass++) {
        if (wc == pass) {
            #pragma unroll
            for (int mi = 0; mi < 4; mi++)
                #pragma unroll
                for (int ni = 0; ni < 4; ni++) {
                    int colL = ni*16 + l15;
                    int row0 = wr*64 + mi*16 + l4*4;
                    f32x4 v = acc[mi][ni];
                    f32x4 sv;
                    #pragma unroll
                    for (int r = 0; r < 4; r++) sv[r] = fmaxf(v[r] + bsh[ni], 0.f);
                    *(f32x4*)(shf + colL*132 + row0) = sv;
                }
        }
        __syncthreads();
        #pragma unroll 4
        for (int i = 0; i < 32; i++) {
            int c = chalf*32 + i;
            float v = shf[c*132 + rr];
            const float* wrow = sW + (pass*64 + c)*20;
            #pragma unroll
            for (int o = 0; o < 18; o++) a18[o] += v * wrow[o];
        }
        __syncthreads();
    }
    const int pixel = mtile*128 + rr;
    float* lo = out + (size_t)pixel*6;
    float* dl = out + DELTA_BASE + (size_t)pixel*12;
    #pragma unroll
    for (int o = 0; o < 6; o++)  atomicAdd(lo + o, a18[o]);
    #pragma unroll
    for (int o = 0; o < 12; o++) atomicAdd(dl + o, a18[6 + o]);
}

__global__ __launch_bounds__(256) void k_finalize(float* __restrict__ out,
                                                  const float* __restrict__ b_cls,
                                                  const float* __restrict__ b_dlt) {
    int pix = blockIdx.x*256 + threadIdx.x;
    if (pix >= NPIX) return;
    float* lo = out + (size_t)pix*6;
    float* pr = out + (size_t)LOGITS_N + (size_t)pix*6;
    float* dl = out + (size_t)DELTA_BASE + (size_t)pix*12;
    #pragma unroll
    for (int a = 0; a < 3; a++) {
        float l0 = lo[a*2]   + b_cls[a*2];
        float l1 = lo[a*2+1] + b_cls[a*2+1];
        lo[a*2] = l0; lo[a*2+1] = l1;
        float m = fmaxf(l0, l1);
        float e0 = __expf(l0 - m), e1 = __expf(l1 - m);
        float inv = 1.f / (e0 + e1);
        pr[a*2] = e0*inv; pr[a*2+1] = e1*inv;
    }
    #pragma unroll
    for (int o = 0; o < 12; o++) dl[o] += b_dlt[o];
}

extern "C" void kernel_launch(void* const* d_in, const int* in_sizes, int n_in,
                              void* d_out, int out_size, void* d_ws, size_t ws_size,
                              hipStream_t stream) {
    const float* in    = (const float*)d_in[0];
    const float* w_sh  = (const float*)d_in[1];
    const float* b_sh  = (const float*)d_in[2];
    const float* w_cls = (const float*)d_in[3];
    const float* b_cls = (const float*)d_in[4];
    const float* w_dlt = (const float*)d_in[5];
    const float* b_dlt = (const float*)d_in[6];
    float* out = (float*)d_out;

    const size_t in_p_elems = (size_t)BATCH*HP*HP*CIN;   // 17,305,600
    const size_t wt_elems   = (size_t)9*CO*CIN;          // 1,179,648
    const size_t part_elems = (size_t)2*NPIX*18;         // 2,359,296
    const size_t need = (in_p_elems + wt_elems)*2 + part_elems*4;  // ~46.4 MB

    if (ws_size >= need) {
        unsigned short* in_p = (unsigned short*)d_ws;
        unsigned short* wt   = in_p + in_p_elems;
        float* part = (float*)(wt + wt_elems);
        hipFuncSetAttribute((const void*)k_main8,
                            hipFuncAttributeMaxDynamicSharedMemorySize, 87040);
        int padq = (int)(((size_t)BATCH*HP*HP*64 + 255)/256);
        k_pad_convert<<<padq, 256, 0, stream>>>(in, in_p);
        k_wt_convert<<<9*CO, 256, 0, stream>>>(w_sh, wt);
        k_main8<<<512, 512, 87040, stream>>>(in_p, wt, b_sh, w_cls, w_dlt, part);
        k_finalize_ws<<<(NPIX + 255)/256, 256, 0, stream>>>(part, out, b_cls, b_dlt);
    } else {
        hipMemsetAsync(d_out, 0, (size_t)out_size * sizeof(float), stream);
        k_main_fb<<<2048, 256, 0, stream>>>(in, w_sh, b_sh, w_cls, w_dlt, out);
        k_finalize<<<(NPIX + 255)/256, 256, 0, stream>>>(out, b_cls, b_dlt);
    }
}

// Round 11
// 224.486 us; speedup vs baseline: 1.6941x; 1.6941x over previous
//
#include <hip/hip_runtime.h>
#include <stdint.h>

#define BATCH 4
#define HH 128
#define WW 128
#define CIN 256
#define CO 512
#define HP 130
#define NPIX (BATCH*HH*WW)          // 65536
#define LOGITS_N (NPIX*6)           // 393216
#define DELTA_BASE (2*LOGITS_N)     // 786432

typedef short bf16x8 __attribute__((ext_vector_type(8)));
typedef unsigned short u16x8 __attribute__((ext_vector_type(8)));
typedef float f32x4 __attribute__((ext_vector_type(4)));
typedef float f32x16 __attribute__((ext_vector_type(16)));
typedef unsigned int u32;

__device__ __forceinline__ unsigned short f2bf(float f) {
    union { float f; unsigned int u; } v; v.f = f;
    return (unsigned short)((v.u + 0x7FFFu + ((v.u >> 16) & 1u)) >> 16);
}

__device__ __forceinline__ void gload16(const unsigned short* g, char* l) {
    __builtin_amdgcn_global_load_lds(
        (const __attribute__((address_space(1))) u32*)g,
        (__attribute__((address_space(3))) u32*)l, 16, 0, 0);
}

// ---- pass 1a: fp32 input -> bf16 with 1-pixel zero halo: [B][130][130][256]
__global__ __launch_bounds__(256) void k_pad_convert(const float* __restrict__ in,
                                                     unsigned short* __restrict__ out) {
    size_t q = (size_t)blockIdx.x*256 + threadIdx.x;     // quad index (4 channels)
    if (q >= (size_t)BATCH*HP*HP*64) return;
    int c4 = ((int)q & 63) * 4;
    int pix = (int)(q >> 6);
    int xx = pix % HP; int t = pix / HP; int yy = t % HP; int b = t / HP;
    ushort4 r = {0, 0, 0, 0};
    if (yy >= 1 && yy <= HH && xx >= 1 && xx <= WW) {
        const float4 v = *(const float4*)(in + (((size_t)(b*HH) + (yy-1))*WW + (xx-1))*CIN + c4);
        r.x = f2bf(v.x); r.y = f2bf(v.y); r.z = f2bf(v.z); r.w = f2bf(v.w);
    }
    *(ushort4*)(out + (size_t)pix*CIN + c4) = r;
}

// ---- pass 1b: w_shared [9][256][512] fp32 -> wT [9][512][256] bf16
__global__ __launch_bounds__(256) void k_wt_convert(const float* __restrict__ w,
                                                    unsigned short* __restrict__ wt) {
    int n = blockIdx.x % CO; int tap = blockIdx.x / CO;
    int c = threadIdx.x;
    wt[((size_t)tap*CO + n)*CIN + c] = f2bf(w[((size_t)tap*CIN + c)*CO + n]);
}

// ==== main: 256x256 tile, round-8 schedule, 32x32x16 MFMA ====
// 512 thr, 8 waves (2M x 4N); per wave 128x64 out = 4mi x 2ni tiles of 32x32.
// LDS: 2 bufs x [A 256x64 | B 256x64] bf16 = 128 KiB dynamic (87KB epilogue reuse).
// Step s: ds_reads from buf[cur], stages (s+1) into buf[cur^1]; counted vmcnt, 1 barrier.
__global__ __launch_bounds__(512, 2) void k_main8(
    const unsigned short* __restrict__ in_p,   // bf16 padded input
    const unsigned short* __restrict__ wt,     // bf16 wT [9][512][256]
    const float* __restrict__ b_sh,
    const float* __restrict__ w_cls,
    const float* __restrict__ w_dlt,
    float* __restrict__ part)                  // [2][NPIX][18]
{
    extern __shared__ char LDS[];

    const int tid  = threadIdx.x;
    const int lane = tid & 63, wave = tid >> 6;
    const int l31  = lane & 31, l5 = lane >> 5;
    const int wm   = wave >> 2, wn = wave & 3;

    // XCD-contiguous bijective swizzle (512 % 8 == 0)
    const int bid   = ((blockIdx.x & 7) << 6) + (blockIdx.x >> 3);
    const int ntile = bid & 1, mtile = bid >> 1;
    const int n0 = ntile << 8;
    const int b  = mtile >> 6;
    const int y0 = (mtile & 63) * 2;           // tile covers image rows y0, y0+1

    // per-thread A/B staging offset (inverse XOR on source; linear LDS dest)
    const int rl0 = tid >> 3, pc0 = tid & 7;
    const int kc0 = pc0 ^ (rl0 & 7);
    const int off = rl0*256 + kc0*8;           // elements
    const int t16 = tid*16;                    // LDS dest byte offset

    // 32x32x16 fragment LDS byte offsets (XOR-swizzled); A row / B col = l31, k = ks*16+l5*8
    int base_a[4], base_b[4];
    #pragma unroll
    for (int ks = 0; ks < 4; ks++) {
        int kbyte = (ks*32 + l5*16) ^ ((l31 & 7) << 4);
        base_a[ks] = (wm*128 + l31)*128 + kbyte;
        base_b[ks] = 32768 + (wn*64 + l31)*128 + kbyte;
    }

    f32x16 acc[4][2];
    #pragma unroll
    for (int mi = 0; mi < 4; mi++)
        #pragma unroll
        for (int ni = 0; ni < 2; ni++)
            #pragma unroll
            for (int r = 0; r < 16; r++) acc[mi][ni][r] = 0.f;

    // ---- prologue: stage tile 0 into buf0 (order: B x4, A-HT2 x2, A-HT3 x2)
    {
        const unsigned short* gB0 = wt + (size_t)n0*256;
        const unsigned short* gA0 = in_p + ((size_t)(b*HP + y0))*HP*256;
        gload16(gB0 + off,          LDS + 32768 + t16);
        gload16(gB0 + 16384 + off,  LDS + 40960 + t16);
        gload16(gB0 + 32768 + off,  LDS + 49152 + t16);
        gload16(gB0 + 49152 + off,  LDS + 57344 + t16);
        gload16(gA0 + off,          LDS + t16);            // HT2: rows 0-63
        gload16(gA0 + 33280 + off,  LDS + 16384 + t16);    //      rows 128-191
        gload16(gA0 + 16384 + off,  LDS + 8192 + t16);     // HT3: rows 64-127
        gload16(gA0 + 49664 + off,  LDS + 24576 + t16);    //      rows 192-255
    }
    asm volatile("s_waitcnt vmcnt(2)" ::: "memory");      // B + HT2 landed; HT3 may fly
    __builtin_amdgcn_sched_barrier(0);
    __builtin_amdgcn_s_barrier();
    __builtin_amdgcn_sched_barrier(0);

#define LOAD_A2(DST, MI0)                                                      \
    _Pragma("unroll")                                                          \
    for (int ks = 0; ks < 4; ks++) {                                           \
        DST[0][ks] = *(const bf16x8*)(bufc + base_a[ks] + (MI0)*4096);         \
        DST[1][ks] = *(const bf16x8*)(bufc + base_a[ks] + ((MI0)+1)*4096);     \
    }

#define LOAD_B8()                                                              \
    _Pragma("unroll")                                                          \
    for (int ks = 0; ks < 4; ks++) {                                           \
        breg[0][ks] = *(const bf16x8*)(bufc + base_b[ks]);                     \
        breg[1][ks] = *(const bf16x8*)(bufc + base_b[ks] + 4096);              \
    }

#define MFMA_G(A2, MI0)                                                        \
    __builtin_amdgcn_s_setprio(1);                                             \
    _Pragma("unroll")                                                          \
    for (int ks = 0; ks < 4; ks++)                                             \
        _Pragma("unroll")                                                      \
        for (int m2 = 0; m2 < 2; m2++)                                         \
            _Pragma("unroll")                                                  \
            for (int ni = 0; ni < 2; ni++)                                     \
                acc[(MI0)+m2][ni] = __builtin_amdgcn_mfma_f32_32x32x16_bf16(   \
                    A2[m2][ks], breg[ni][ks], acc[(MI0)+m2][ni], 0, 0, 0);     \
    __builtin_amdgcn_s_setprio(0);

    for (int s = 0; s < 36; ++s) {
        const int s1 = s + 1;
        const int tap1 = s1 >> 2, kq1 = s1 & 3;
        const int dy1 = (tap1*11) >> 5, dx1 = tap1 - dy1*3;
        const unsigned short* gA = in_p + ((size_t)((b*HP + y0 + dy1)*HP + dx1))*256 + kq1*64;
        const unsigned short* gB = wt + ((size_t)(tap1*512 + n0))*256 + kq1*64;
        const int cur = s & 1;
        const char* bufc = LDS + (cur << 16);
        char* Ad = LDS + ((cur ^ 1) << 16);
        char* Bd = Ad + 32768;
        const bool more = (s < 35);

        bf16x8 aA[2][4], aB[2][4], breg[2][4];

        // group 1 reads (A rows in HT2) + all B; stage B(s+1)
        LOAD_A2(aA, 0)
        LOAD_B8()
        __builtin_amdgcn_sched_barrier(0);
        if (more) {
            gload16(gB + off,          Bd + t16);
            gload16(gB + 16384 + off,  Bd + 8192 + t16);
            gload16(gB + 32768 + off,  Bd + 16384 + t16);
            gload16(gB + 49152 + off,  Bd + 24576 + t16);
        }
        __builtin_amdgcn_sched_barrier(0);
        MFMA_G(aA, 0)

        // HT3(s) must be landed before mi2/3 reads (rows 64-127 / 192-255).
        // Outstanding newer per wave: the 4 B-stages just issued (0 at s=35).
        if (more) { asm volatile("s_waitcnt vmcnt(4)" ::: "memory"); }
        else      { asm volatile("s_waitcnt vmcnt(0)" ::: "memory"); }
        __builtin_amdgcn_sched_barrier(0);

        LOAD_A2(aB, 2)
        if (more) {
            gload16(gA + off,          Ad + t16);
            gload16(gA + 33280 + off,  Ad + 16384 + t16);
            gload16(gA + 16384 + off,  Ad + 8192 + t16);
            gload16(gA + 49664 + off,  Ad + 24576 + t16);
        }
        __builtin_amdgcn_sched_barrier(0);
        MFMA_G(aB, 2)

        // boundary: B(s+1)+HT2(s+1) landed (HT3(s+1) may fly); bufc reads retired
        if (more) { asm volatile("s_waitcnt vmcnt(2)" ::: "memory"); }
        __builtin_amdgcn_sched_barrier(0);
        __builtin_amdgcn_s_barrier();
        __builtin_amdgcn_sched_barrier(0);
    }
#undef LOAD_A2
#undef LOAD_B8
#undef MFMA_G

    // ---- epilogue: bias+ReLU + 1x1-head partial reduction over this block's 256 channels
    // C/D 32x32 layout: col = lane&31, row = (reg&3) + 8*(reg>>2) + 4*(lane>>5)
    float* shf = (float*)LDS;                  // [64 cols][260]
    float* sW  = (float*)(LDS + 66560);        // [256][20]
    for (int j = tid; j < 256*18; j += 512) {
        int c = j / 18, o = j - c*18;
        sW[c*20 + o] = (o < 6) ? w_cls[(size_t)(n0 + c)*6 + o]
                               : w_dlt[(size_t)(n0 + c)*12 + (o - 6)];
    }
    float bsh[2];
    #pragma unroll
    for (int ni = 0; ni < 2; ni++) bsh[ni] = b_sh[n0 + wn*64 + ni*32 + l31];

    float a18[18];
    #pragma unroll
    for (int o = 0; o < 18; o++) a18[o] = 0.f;
    const int rr = tid & 255, chalf = tid >> 8;
    __syncthreads();

    for (int p = 0; p < 4; ++p) {
        if (wn == p) {
            #pragma unroll
            for (int mi = 0; mi < 4; mi++)
                #pragma unroll
                for (int ni = 0; ni < 2; ni++) {
                    int colL = ni*32 + l31;
                    #pragma unroll
                    for (int rg = 0; rg < 4; rg++) {
                        int row0 = wm*128 + mi*32 + rg*8 + l5*4;
                        f32x4 sv;
                        #pragma unroll
                        for (int r = 0; r < 4; r++)
                            sv[r] = fmaxf(acc[mi][ni][rg*4 + r] + bsh[ni], 0.f);
                        *(f32x4*)(shf + colL*260 + row0) = sv;
                    }
                }
        }
        __syncthreads();
        #pragma unroll 4
        for (int i = 0; i < 32; i++) {
            int c = chalf*32 + i;
            float v = shf[c*260 + rr];
            const float* wrow = sW + (p*64 + c)*20;
            #pragma unroll
            for (int o = 0; o < 18; o++) a18[o] += v * wrow[o];
        }
        __syncthreads();
    }

    if (chalf == 1) {
        #pragma unroll
        for (int o = 0; o < 18; o++) shf[rr*18 + o] = a18[o];
    }
    __syncthreads();
    if (chalf == 0) {
        float* dst = part + ((size_t)ntile*NPIX + (size_t)mtile*256 + rr)*18;
        #pragma unroll
        for (int o = 0; o < 18; o++) dst[o] = a18[o] + shf[rr*18 + o];
    }
}

// ---- finalize (ws path): sum 2 partials, biases, softmax -> all outputs
__global__ __launch_bounds__(256) void k_finalize_ws(const float* __restrict__ part,
                                                     float* __restrict__ out,
                                                     const float* __restrict__ b_cls,
                                                     const float* __restrict__ b_dlt) {
    int pix = blockIdx.x*256 + threadIdx.x;
    if (pix >= NPIX) return;
    float s[18];
    #pragma unroll
    for (int o = 0; o < 18; o++)
        s[o] = part[(size_t)pix*18 + o] + part[((size_t)NPIX + pix)*18 + o];
    float* lo = out + (size_t)pix*6;
    float* pr = out + (size_t)LOGITS_N + (size_t)pix*6;
    float* dl = out + (size_t)DELTA_BASE + (size_t)pix*12;
    #pragma unroll
    for (int a = 0; a < 3; a++) {
        float l0 = s[a*2]   + b_cls[a*2];
        float l1 = s[a*2+1] + b_cls[a*2+1];
        lo[a*2] = l0; lo[a*2+1] = l1;
        float m = fmaxf(l0, l1);
        float e0 = __expf(l0 - m), e1 = __expf(l1 - m);
        float inv = 1.f / (e0 + e1);
        pr[a*2] = e0*inv; pr[a*2+1] = e1*inv;
    }
    #pragma unroll
    for (int o = 0; o < 12; o++) dl[o] = s[6 + o] + b_dlt[o];
}

// ======== fallback path (no workspace): round-2 proven kernel, atomics ========
__global__ __launch_bounds__(256) void k_main_fb(
    const float* __restrict__ in_f, const float* __restrict__ w_f,
    const float* __restrict__ b_sh, const float* __restrict__ w_cls,
    const float* __restrict__ w_dlt, float* __restrict__ out)
{
    __shared__ float smemf[11008];
    char* smem  = (char*)smemf;
    char* smemB = smem + 16384;
    const int tid = threadIdx.x;
    const int lane = tid & 63, wave = tid >> 6;
    const int l15 = lane & 15, l4 = lane >> 4;
    const int wr = wave >> 1, wc = wave & 1;
    int bid = ((blockIdx.x & 7) << 8) + (blockIdx.x >> 3);
    const int ntile = bid & 3, mtile = bid >> 2;
    const int n0 = ntile << 7;
    const int b = mtile >> 7, y = mtile & 127;
    int aoff[4][2], boff[4][2];
    #pragma unroll
    for (int mi = 0; mi < 4; mi++) {
        int rowA = wr*64 + mi*16 + l15;
        int rowB = wc*64 + mi*16 + l15;
        #pragma unroll
        for (int kk = 0; kk < 2; kk++) {
            int kb = (kk*32 + l4*8) * 2;
            aoff[mi][kk] = rowA*128 + (kb ^ ((rowA & 7) << 4));
            boff[mi][kk] = rowB*128 + (kb ^ ((rowB & 7) << 4));
        }
    }
    f32x4 acc[4][4];
    const f32x4 zz = {0.f, 0.f, 0.f, 0.f};
    #pragma unroll
    for (int mi = 0; mi < 4; mi++)
        #pragma unroll
        for (int ni = 0; ni < 4; ni++) acc[mi][ni] = zz;
    for (int s = 0; s < 36; s++) {
        int tap = s >> 2, kq = s & 3;
        int dy = tap / 3, dx = tap - dy*3;
        const int c0 = kq * 64;
        const int yy = y + dy - 1;
        const bool yok = (yy >= 0) && (yy < HH);
        #pragma unroll
        for (int i = 0; i < 4; i++) {
            int ci = i*256 + tid;
            int row = ci >> 3, pc = ci & 7;
            int kc = pc ^ (row & 7);
            int xx = row + dx - 1;
            u16x8 a;
            if (yok && xx >= 0 && xx < WW) {
                const float* sp = in_f + (((size_t)(b*HH) + yy)*WW + xx)*CIN + c0 + kc*8;
                #pragma unroll
                for (int j = 0; j < 8; j++) a[j] = (short)f2bf(sp[j]);
            } else {
                #pragma unroll
                for (int j = 0; j < 8; j++) a[j] = 0;
            }
            *(u16x8*)(smem + ci*16) = a;
            const float* wsrc = w_f + ((size_t)(tap*CIN + c0 + kc*8))*CO + n0 + row;
            u16x8 bb;
            #pragma unroll
            for (int j = 0; j < 8; j++) bb[j] = (short)f2bf(wsrc[(size_t)j*CO]);
            *(u16x8*)(smemB + ci*16) = bb;
        }
        __syncthreads();
        #pragma unroll
        for (int kk = 0; kk < 2; kk++) {
            bf16x8 av[4], bv[4];
            #pragma unroll
            for (int mi = 0; mi < 4; mi++) av[mi] = *(const bf16x8*)(smem  + aoff[mi][kk]);
            #pragma unroll
            for (int ni = 0; ni < 4; ni++) bv[ni] = *(const bf16x8*)(smemB + boff[ni][kk]);
            #pragma unroll
            for (int mi = 0; mi < 4; mi++)
                #pragma unroll
                for (int ni = 0; ni < 4; ni++)
                    acc[mi][ni] = __builtin_amdgcn_mfma_f32_16x16x32_bf16(
                        av[mi], bv[ni], acc[mi][ni], 0, 0, 0);
        }
        __syncthreads();
    }
    float* shf = smemf;
    float* sW  = smemf + 8448;
    for (int j = tid; j < 128*18; j += 256) {
        int c = j / 18, o = j - c*18;
        sW[c*20 + o] = (o < 6) ? w_cls[(size_t)(n0 + c)*6 + o]
                               : w_dlt[(size_t)(n0 + c)*12 + (o - 6)];
    }
    float bsh[4];
    #pragma unroll
    for (int ni = 0; ni < 4; ni++) bsh[ni] = b_sh[n0 + wc*64 + ni*16 + l15];
    float a18[18];
    #pragma unroll
    for (int o = 0; o < 18; o++) a18[o] = 0.f;
    const int rr = tid & 127, chalf = tid >> 7;
    #pragma unroll
    for (int pass = 0; pass < 2; pass++) {
        if (wc == pass) {
            #pragma unroll
            for (int mi = 0; mi < 4; mi++)
                #pragma unroll
                for (int ni = 0; ni < 4; ni++) {
                    int colL = ni*16 + l15;
                    int row0 = wr*64 + mi*16 + l4*4;
                    f32x4 v = acc[mi][ni];
                    f32x4 sv;
                    #pragma unroll
                    for (int r = 0; r < 4; r++) sv[r] = fmaxf(v[r] + bsh[ni], 0.f);
                    *(f32x4*)(shf + colL*132 + row0) = sv;
                }
        }
        __syncthreads();
        #pragma unroll 4
        for (int i = 0; i < 32; i++) {
            int c = chalf*32 + i;
            float v = shf[c*132 + rr];
            const float* wrow = sW + (pass*64 + c)*20;
            #pragma unroll
            for (int o = 0; o < 18; o++) a18[o] += v * wrow[o];
        }
        __syncthreads();
    }
    const int pixel = mtile*128 + rr;
    float* lo = out + (size_t)pixel*6;
    float* dl = out + DELTA_BASE + (size_t)pixel*12;
    #pragma unroll
    for (int o = 0; o < 6; o++)  atomicAdd(lo + o, a18[o]);
    #pragma unroll
    for (int o = 0; o < 12; o++) atomicAdd(dl + o, a18[6 + o]);
}

__global__ __launch_bounds__(256) void k_finalize(float* __restrict__ out,
                                                  const float* __restrict__ b_cls,
                                                  const float* __restrict__ b_dlt) {
    int pix = blockIdx.x*256 + threadIdx.x;
    if (pix >= NPIX) return;
    float* lo = out + (size_t)pix*6;
    float* pr = out + (size_t)LOGITS_N + (size_t)pix*6;
    float* dl = out + (size_t)DELTA_BASE + (size_t)pix*12;
    #pragma unroll
    for (int a = 0; a < 3; a++) {
        float l0 = lo[a*2]   + b_cls[a*2];
        float l1 = lo[a*2+1] + b_cls[a*2+1];
        lo[a*2] = l0; lo[a*2+1] = l1;
        float m = fmaxf(l0, l1);
        float e0 = __expf(l0 - m), e1 = __expf(l1 - m);
        float inv = 1.f / (e0 + e1);
        pr[a*2] = e0*inv; pr[a*2+1] = e1*inv;
    }
    #pragma unroll
    for (int o = 0; o < 12; o++) dl[o] += b_dlt[o];
}

extern "C" void kernel_launch(void* const* d_in, const int* in_sizes, int n_in,
                              void* d_out, int out_size, void* d_ws, size_t ws_size,
                              hipStream_t stream) {
    const float* in    = (const float*)d_in[0];
    const float* w_sh  = (const float*)d_in[1];
    const float* b_sh  = (const float*)d_in[2];
    const float* w_cls = (const float*)d_in[3];
    const float* b_cls = (const float*)d_in[4];
    const float* w_dlt = (const float*)d_in[5];
    const float* b_dlt = (const float*)d_in[6];
    float* out = (float*)d_out;

    const size_t in_p_elems = (size_t)BATCH*HP*HP*CIN;   // 17,305,600
    const size_t wt_elems   = (size_t)9*CO*CIN;          // 1,179,648
    const size_t part_elems = (size_t)2*NPIX*18;         // 2,359,296
    const size_t need = (in_p_elems + wt_elems)*2 + part_elems*4;  // ~46.4 MB

    if (ws_size >= need) {
        unsigned short* in_p = (unsigned short*)d_ws;
        unsigned short* wt   = in_p + in_p_elems;
        float* part = (float*)(wt + wt_elems);
        hipFuncSetAttribute((const void*)k_main8,
                            hipFuncAttributeMaxDynamicSharedMemorySize, 131072);
        int padq = (int)(((size_t)BATCH*HP*HP*64 + 255)/256);
        k_pad_convert<<<padq, 256, 0, stream>>>(in, in_p);
        k_wt_convert<<<9*CO, 256, 0, stream>>>(w_sh, wt);
        k_main8<<<512, 512, 131072, stream>>>(in_p, wt, b_sh, w_cls, w_dlt, part);
        k_finalize_ws<<<(NPIX + 255)/256, 256, 0, stream>>>(part, out, b_cls, b_dlt);
    } else {
        hipMemsetAsync(d_out, 0, (size_t)out_size * sizeof(float), stream);
        k_main_fb<<<2048, 256, 0, stream>>>(in, w_sh, b_sh, w_cls, w_dlt, out);
        k_finalize<<<(NPIX + 255)/256, 256, 0, stream>>>(out, b_cls, b_dlt);
    }
}

// Round 12
// 192.443 us; speedup vs baseline: 1.9762x; 1.1665x over previous
//
#include <hip/hip_runtime.h>
#include <stdint.h>

#define BATCH 4
#define HH 128
#define WW 128
#define CIN 256
#define CO 512
#define HP 130
#define NPIX (BATCH*HH*WW)          // 65536
#define LOGITS_N (NPIX*6)           // 393216
#define DELTA_BASE (2*LOGITS_N)     // 786432

typedef short bf16x8 __attribute__((ext_vector_type(8)));
typedef unsigned short u16x8 __attribute__((ext_vector_type(8)));
typedef float f32x4 __attribute__((ext_vector_type(4)));
typedef unsigned int u32;

__device__ __forceinline__ unsigned short f2bf(float f) {
    union { float f; unsigned int u; } v; v.f = f;
    return (unsigned short)((v.u + 0x7FFFu + ((v.u >> 16) & 1u)) >> 16);
}

__device__ __forceinline__ void gload16(const unsigned short* g, char* l) {
    __builtin_amdgcn_global_load_lds(
        (const __attribute__((address_space(1))) u32*)g,
        (__attribute__((address_space(3))) u32*)l, 16, 0, 0);
}

// ---- pass 1a: fp32 input -> bf16 with 1-pixel zero halo: [B][130][130][256]
__global__ __launch_bounds__(256) void k_pad_convert(const float* __restrict__ in,
                                                     unsigned short* __restrict__ out) {
    size_t q = (size_t)blockIdx.x*256 + threadIdx.x;     // quad index (4 channels)
    if (q >= (size_t)BATCH*HP*HP*64) return;
    int c4 = ((int)q & 63) * 4;
    int pix = (int)(q >> 6);
    int xx = pix % HP; int t = pix / HP; int yy = t % HP; int b = t / HP;
    ushort4 r = {0, 0, 0, 0};
    if (yy >= 1 && yy <= HH && xx >= 1 && xx <= WW) {
        const float4 v = *(const float4*)(in + (((size_t)(b*HH) + (yy-1))*WW + (xx-1))*CIN + c4);
        r.x = f2bf(v.x); r.y = f2bf(v.y); r.z = f2bf(v.z); r.w = f2bf(v.w);
    }
    *(ushort4*)(out + (size_t)pix*CIN + c4) = r;
}

// ---- pass 1b: w_shared [9][256][512] fp32 -> wT [9][512][256] bf16
__global__ __launch_bounds__(256) void k_wt_convert(const float* __restrict__ w,
                                                    unsigned short* __restrict__ wt) {
    int n = blockIdx.x % CO; int tap = blockIdx.x / CO;
    int c = threadIdx.x;
    wt[((size_t)tap*CO + n)*CIN + c] = f2bf(w[((size_t)tap*CIN + c)*CO + n]);
}

// ==== main: 256x256 tile, 16x16x32 MFMA, depth-2 A pipeline ====
// A: TRIPLE buffer (LDS 0/32K/64K), staged 2 steps ahead -> no mid-step wait.
// B: double buffer (LDS 96K/128K), staged 1 step ahead.
// One boundary vmcnt(4) + barrier per step. LDS = 160 KiB exactly.
__global__ __launch_bounds__(512, 2) void k_main8(
    const unsigned short* __restrict__ in_p,   // bf16 padded input
    const unsigned short* __restrict__ wt,     // bf16 wT [9][512][256]
    const float* __restrict__ b_sh,
    const float* __restrict__ w_cls,
    const float* __restrict__ w_dlt,
    float* __restrict__ part)                  // [2][NPIX][18]
{
    extern __shared__ char LDS[];
    char* const BBASE = LDS + 98304;

    const int tid  = threadIdx.x;
    const int lane = tid & 63, wave = tid >> 6;
    const int l15  = lane & 15, l4 = lane >> 4;
    const int wm   = wave >> 2, wn = wave & 3;

    // XCD-contiguous bijective swizzle (512 % 8 == 0)
    const int bid   = ((blockIdx.x & 7) << 6) + (blockIdx.x >> 3);
    const int ntile = bid & 1, mtile = bid >> 1;
    const int n0 = ntile << 8;
    const int b  = mtile >> 6;
    const int y0 = (mtile & 63) * 2;           // tile covers image rows y0, y0+1

    // per-thread staging offset: chunk tid -> row tid>>3, sub tid&7 (inverse XOR on source)
    const int rl0 = tid >> 3, pc0 = tid & 7;
    const int kc0 = pc0 ^ (rl0 & 7);
    const int off = rl0*256 + kc0*8;           // elements
    const int t16 = tid*16;                    // LDS dest byte offset

    // MFMA fragment LDS byte offsets (XOR-swizzled reads), relative to each buffer
    int base_a[2], base_b[2];
    #pragma unroll
    for (int kk = 0; kk < 2; kk++) {
        int swz = ((kk*32 + l4*8)*2) ^ ((l15 & 7) << 4);
        base_a[kk] = (wm*128 + l15)*128 + swz;
        base_b[kk] = (wn*64 + l15)*128 + swz;
    }

    f32x4 acc[8][4];
    const f32x4 zz = {0.f, 0.f, 0.f, 0.f};
    #pragma unroll
    for (int mi = 0; mi < 8; mi++)
        #pragma unroll
        for (int ni = 0; ni < 4; ni++) acc[mi][ni] = zz;

    // ---- prologue: stage A(0) -> Abuf0, B(0) -> Bbuf0, A(1) -> Abuf1
    {
        const unsigned short* gA0 = in_p + ((size_t)(b*HP + y0))*HP*256;       // tap0,kq0
        const unsigned short* gB0 = wt + (size_t)n0*256;
        const unsigned short* gA1 = gA0 + 64;                                  // tap0,kq1
        gload16(gA0 + off,          LDS + t16);
        gload16(gA0 + 16384 + off,  LDS + 8192 + t16);
        gload16(gA0 + 33280 + off,  LDS + 16384 + t16);
        gload16(gA0 + 49664 + off,  LDS + 24576 + t16);
        __builtin_amdgcn_sched_barrier(0);
        gload16(gB0 + off,          BBASE + t16);
        gload16(gB0 + 16384 + off,  BBASE + 8192 + t16);
        gload16(gB0 + 32768 + off,  BBASE + 16384 + t16);
        gload16(gB0 + 49152 + off,  BBASE + 24576 + t16);
        __builtin_amdgcn_sched_barrier(0);
        gload16(gA1 + off,          LDS + 32768 + t16);
        gload16(gA1 + 16384 + off,  LDS + 40960 + t16);
        gload16(gA1 + 33280 + off,  LDS + 49152 + t16);
        gload16(gA1 + 49664 + off,  LDS + 57344 + t16);
    }
    asm volatile("s_waitcnt vmcnt(4)" ::: "memory");      // A(0)+B(0) landed; A(1) may fly
    __builtin_amdgcn_sched_barrier(0);
    __builtin_amdgcn_s_barrier();
    __builtin_amdgcn_sched_barrier(0);

#define MFMA_Q(Q, AQ)                                                        \
    __builtin_amdgcn_s_setprio(1);                                           \
    _Pragma("unroll")                                                        \
    for (int kk = 0; kk < 2; kk++)                                           \
        _Pragma("unroll")                                                    \
        for (int mm = 0; mm < 2; mm++)                                       \
            _Pragma("unroll")                                                \
            for (int ni = 0; ni < 4; ni++)                                   \
                acc[2*(Q)+mm][ni] = __builtin_amdgcn_mfma_f32_16x16x32_bf16( \
                    AQ[mm][kk], breg[ni][kk], acc[2*(Q)+mm][ni], 0, 0, 0);   \
    __builtin_amdgcn_s_setprio(0);

#define LOAD_Q(AQ, Q)                                                        \
    _Pragma("unroll")                                                        \
    for (int kk = 0; kk < 2; kk++) {                                         \
        AQ[0][kk] = *(const bf16x8*)(bufA + base_a[kk] + (2*(Q))*2048);      \
        AQ[1][kk] = *(const bf16x8*)(bufA + base_a[kk] + (2*(Q)+1)*2048);    \
    }

    int ia = 0;                                 // A read buffer index (s % 3)
    for (int s = 0; s < 36; ++s) {
        // B(s+1) source
        const int s1 = s + 1;
        const int tapB = s1 >> 2, kqB = s1 & 3;
        const unsigned short* gB = wt + ((size_t)(tapB*512 + n0))*256 + kqB*64;
        // A(s+2) source
        const int s2p = s + 2;
        const int tapA = s2p >> 2, kqA = s2p & 3;
        const int dyA = (tapA*11) >> 5, dxA = tapA - dyA*3;
        const unsigned short* gA = in_p + ((size_t)((b*HP + y0 + dyA)*HP + dxA))*256 + kqA*64;

        const char* bufA = LDS + (ia << 15);
        const char* bufB = BBASE + ((s & 1) << 15);
        int iw = ia + 2; if (iw > 2) iw -= 3;
        char* Ad = LDS + (iw << 15);
        char* Bd = BBASE + ((s1 & 1) << 15);
        const bool moreB = (s < 35), moreA = (s < 34);

        bf16x8 breg[4][2];
        #pragma unroll
        for (int kk = 0; kk < 2; kk++) {
            breg[0][kk] = *(const bf16x8*)(bufB + base_b[kk]);
            breg[1][kk] = *(const bf16x8*)(bufB + base_b[kk] + 2048);
            breg[2][kk] = *(const bf16x8*)(bufB + base_b[kk] + 4096);
            breg[3][kk] = *(const bf16x8*)(bufB + base_b[kk] + 6144);
        }
        bf16x8 a0[2][2], a1[2][2], a2[2][2], a3[2][2];
        LOAD_Q(a0, 0)
        __builtin_amdgcn_sched_barrier(0);
        if (moreB) {
            gload16(gB + off,          Bd + t16);
            gload16(gB + 16384 + off,  Bd + 8192 + t16);
            gload16(gB + 32768 + off,  Bd + 16384 + t16);
            gload16(gB + 49152 + off,  Bd + 24576 + t16);
        }
        __builtin_amdgcn_sched_barrier(0);
        LOAD_Q(a1, 1)
        MFMA_Q(0, a0)
        LOAD_Q(a2, 2)
        if (moreA) {
            gload16(gA + off,          Ad + t16);
            gload16(gA + 16384 + off,  Ad + 8192 + t16);
            gload16(gA + 33280 + off,  Ad + 16384 + t16);
            gload16(gA + 49664 + off,  Ad + 24576 + t16);
        }
        __builtin_amdgcn_sched_barrier(0);
        MFMA_Q(1, a1)
        LOAD_Q(a3, 3)
        MFMA_Q(2, a2)
        MFMA_Q(3, a3)

        // boundary: A(s+1)+B(s+1) landed; A(s+2) (4 loads) may fly
        if (moreA)      { asm volatile("s_waitcnt vmcnt(4)" ::: "memory"); }
        else if (moreB) { asm volatile("s_waitcnt vmcnt(0)" ::: "memory"); }
        __builtin_amdgcn_sched_barrier(0);
        __builtin_amdgcn_s_barrier();
        __builtin_amdgcn_sched_barrier(0);

        ia = ia == 2 ? 0 : ia + 1;
    }
#undef MFMA_Q
#undef LOAD_Q

    // ---- epilogue: bias+ReLU + 1x1-head partial reduction over this block's 256 channels
    float* shf = (float*)LDS;                  // [64 cols][260]
    float* sW  = (float*)(LDS + 66560);        // [256][20]
    for (int j = tid; j < 256*18; j += 512) {
        int c = j / 18, o = j - c*18;
        sW[c*20 + o] = (o < 6) ? w_cls[(size_t)(n0 + c)*6 + o]
                               : w_dlt[(size_t)(n0 + c)*12 + (o - 6)];
    }
    float bsh[4];
    #pragma unroll
    for (int ni = 0; ni < 4; ni++) bsh[ni] = b_sh[n0 + wn*64 + ni*16 + l15];

    float a18[18];
    #pragma unroll
    for (int o = 0; o < 18; o++) a18[o] = 0.f;
    const int rr = tid & 255, chalf = tid >> 8;
    __syncthreads();

    for (int p = 0; p < 4; ++p) {
        if (wn == p) {
            #pragma unroll
            for (int mi = 0; mi < 8; mi++)
                #pragma unroll
                for (int ni = 0; ni < 4; ni++) {
                    int colL = ni*16 + l15;
                    int row0 = wm*128 + mi*16 + l4*4;
                    f32x4 v = acc[mi][ni];
                    f32x4 sv;
                    #pragma unroll
                    for (int r = 0; r < 4; r++) sv[r] = fmaxf(v[r] + bsh[ni], 0.f);
                    *(f32x4*)(shf + colL*260 + row0) = sv;
                }
        }
        __syncthreads();
        #pragma unroll 4
        for (int i = 0; i < 32; i++) {
            int c = chalf*32 + i;
            float v = shf[c*260 + rr];
            const float* wrow = sW + (p*64 + c)*20;
            #pragma unroll
            for (int o = 0; o < 18; o++) a18[o] += v * wrow[o];
        }
        __syncthreads();
    }

    if (chalf == 1) {
        #pragma unroll
        for (int o = 0; o < 18; o++) shf[rr*18 + o] = a18[o];
    }
    __syncthreads();
    if (chalf == 0) {
        float* dst = part + ((size_t)ntile*NPIX + (size_t)mtile*256 + rr)*18;
        #pragma unroll
        for (int o = 0; o < 18; o++) dst[o] = a18[o] + shf[rr*18 + o];
    }
}

// ---- finalize (ws path): sum 2 partials, biases, softmax -> all outputs
__global__ __launch_bounds__(256) void k_finalize_ws(const float* __restrict__ part,
                                                     float* __restrict__ out,
                                                     const float* __restrict__ b_cls,
                                                     const float* __restrict__ b_dlt) {
    int pix = blockIdx.x*256 + threadIdx.x;
    if (pix >= NPIX) return;
    float s[18];
    #pragma unroll
    for (int o = 0; o < 18; o++)
        s[o] = part[(size_t)pix*18 + o] + part[((size_t)NPIX + pix)*18 + o];
    float* lo = out + (size_t)pix*6;
    float* pr = out + (size_t)LOGITS_N + (size_t)pix*6;
    float* dl = out + (size_t)DELTA_BASE + (size_t)pix*12;
    #pragma unroll
    for (int a = 0; a < 3; a++) {
        float l0 = s[a*2]   + b_cls[a*2];
        float l1 = s[a*2+1] + b_cls[a*2+1];
        lo[a*2] = l0; lo[a*2+1] = l1;
        float m = fmaxf(l0, l1);
        float e0 = __expf(l0 - m), e1 = __expf(l1 - m);
        float inv = 1.f / (e0 + e1);
        pr[a*2] = e0*inv; pr[a*2+1] = e1*inv;
    }
    #pragma unroll
    for (int o = 0; o < 12; o++) dl[o] = s[6 + o] + b_dlt[o];
}

// ======== fallback path (no workspace): round-2 proven kernel, atomics ========
__global__ __launch_bounds__(256) void k_main_fb(
    const float* __restrict__ in_f, const float* __restrict__ w_f,
    const float* __restrict__ b_sh, const float* __restrict__ w_cls,
    const float* __restrict__ w_dlt, float* __restrict__ out)
{
    __shared__ float smemf[11008];
    char* smem  = (char*)smemf;
    char* smemB = smem + 16384;
    const int tid = threadIdx.x;
    const int lane = tid & 63, wave = tid >> 6;
    const int l15 = lane & 15, l4 = lane >> 4;
    const int wr = wave >> 1, wc = wave & 1;
    int bid = ((blockIdx.x & 7) << 8) + (blockIdx.x >> 3);
    const int ntile = bid & 3, mtile = bid >> 2;
    const int n0 = ntile << 7;
    const int b = mtile >> 7, y = mtile & 127;
    int aoff[4][2], boff[4][2];
    #pragma unroll
    for (int mi = 0; mi < 4; mi++) {
        int rowA = wr*64 + mi*16 + l15;
        int rowB = wc*64 + mi*16 + l15;
        #pragma unroll
        for (int kk = 0; kk < 2; kk++) {
            int kb = (kk*32 + l4*8) * 2;
            aoff[mi][kk] = rowA*128 + (kb ^ ((rowA & 7) << 4));
            boff[mi][kk] = rowB*128 + (kb ^ ((rowB & 7) << 4));
        }
    }
    f32x4 acc[4][4];
    const f32x4 zz = {0.f, 0.f, 0.f, 0.f};
    #pragma unroll
    for (int mi = 0; mi < 4; mi++)
        #pragma unroll
        for (int ni = 0; ni < 4; ni++) acc[mi][ni] = zz;
    for (int s = 0; s < 36; s++) {
        int tap = s >> 2, kq = s & 3;
        int dy = tap / 3, dx = tap - dy*3;
        const int c0 = kq * 64;
        const int yy = y + dy - 1;
        const bool yok = (yy >= 0) && (yy < HH);
        #pragma unroll
        for (int i = 0; i < 4; i++) {
            int ci = i*256 + tid;
            int row = ci >> 3, pc = ci & 7;
            int kc = pc ^ (row & 7);
            int xx = row + dx - 1;
            u16x8 a;
            if (yok && xx >= 0 && xx < WW) {
                const float* sp = in_f + (((size_t)(b*HH) + yy)*WW + xx)*CIN + c0 + kc*8;
                #pragma unroll
                for (int j = 0; j < 8; j++) a[j] = (short)f2bf(sp[j]);
            } else {
                #pragma unroll
                for (int j = 0; j < 8; j++) a[j] = 0;
            }
            *(u16x8*)(smem + ci*16) = a;
            const float* wsrc = w_f + ((size_t)(tap*CIN + c0 + kc*8))*CO + n0 + row;
            u16x8 bb;
            #pragma unroll
            for (int j = 0; j < 8; j++) bb[j] = (short)f2bf(wsrc[(size_t)j*CO]);
            *(u16x8*)(smemB + ci*16) = bb;
        }
        __syncthreads();
        #pragma unroll
        for (int kk = 0; kk < 2; kk++) {
            bf16x8 av[4], bv[4];
            #pragma unroll
            for (int mi = 0; mi < 4; mi++) av[mi] = *(const bf16x8*)(smem  + aoff[mi][kk]);
            #pragma unroll
            for (int ni = 0; ni < 4; ni++) bv[ni] = *(const bf16x8*)(smemB + boff[ni][kk]);
            #pragma unroll
            for (int mi = 0; mi < 4; mi++)
                #pragma unroll
                for (int ni = 0; ni < 4; ni++)
                    acc[mi][ni] = __builtin_amdgcn_mfma_f32_16x16x32_bf16(
                        av[mi], bv[ni], acc[mi][ni], 0, 0, 0);
        }
        __syncthreads();
    }
    float* shf = smemf;
    float* sW  = smemf + 8448;
    for (int j = tid; j < 128*18; j += 256) {
        int c = j / 18, o = j - c*18;
        sW[c*20 + o] = (o < 6) ? w_cls[(size_t)(n0 + c)*6 + o]
                               : w_dlt[(size_t)(n0 + c)*12 + (o - 6)];
    }
    float bsh[4];
    #pragma unroll
    for (int ni = 0; ni < 4; ni++) bsh[ni] = b_sh[n0 + wc*64 + ni*16 + l15];
    float a18[18];
    #pragma unroll
    for (int o = 0; o < 18; o++) a18[o] = 0.f;
    const int rr = tid & 127, chalf = tid >> 7;
    #pragma unroll
    for (int pass = 0; pass < 2; pass++) {
        if (wc == pass) {
            #pragma unroll
            for (int mi = 0; mi < 4; mi++)
                #pragma unroll
                for (int ni = 0; ni < 4; ni++) {
                    int colL = ni*16 + l15;
                    int row0 = wr*64 + mi*16 + l4*4;
                    f32x4 v = acc[mi][ni];
                    f32x4 sv;
                    #pragma unroll
                    for (int r = 0; r < 4; r++) sv[r] = fmaxf(v[r] + bsh[ni], 0.f);
                    *(f32x4*)(shf + colL*132 + row0) = sv;
                }
        }
        __syncthreads();
        #pragma unroll 4
        for (int i = 0; i < 32; i++) {
            int c = chalf*32 + i;
            float v = shf[c*132 + rr];
            const float* wrow = sW + (pass*64 + c)*20;
            #pragma unroll
            for (int o = 0; o < 18; o++) a18[o] += v * wrow[o];
        }
        __syncthreads();
    }
    const int pixel = mtile*128 + rr;
    float* lo = out + (size_t)pixel*6;
    float* dl = out + DELTA_BASE + (size_t)pixel*12;
    #pragma unroll
    for (int o = 0; o < 6; o++)  atomicAdd(lo + o, a18[o]);
    #pragma unroll
    for (int o = 0; o < 12; o++) atomicAdd(dl + o, a18[6 + o]);
}

__global__ __launch_bounds__(256) void k_finalize(float* __restrict__ out,
                                                  const float* __restrict__ b_cls,
                                                  const float* __restrict__ b_dlt) {
    int pix = blockIdx.x*256 + threadIdx.x;
    if (pix >= NPIX) return;
    float* lo = out + (size_t)pix*6;
    float* pr = out + (size_t)LOGITS_N + (size_t)pix*6;
    float* dl = out + (size_t)DELTA_BASE + (size_t)pix*12;
    #pragma unroll
    for (int a = 0; a < 3; a++) {
        float l0 = lo[a*2]   + b_cls[a*2];
        float l1 = lo[a*2+1] + b_cls[a*2+1];
        lo[a*2] = l0; lo[a*2+1] = l1;
        float m = fmaxf(l0, l1);
        float e0 = __expf(l0 - m), e1 = __expf(l1 - m);
        float inv = 1.f / (e0 + e1);
        pr[a*2] = e0*inv; pr[a*2+1] = e1*inv;
    }
    #pragma unroll
    for (int o = 0; o < 12; o++) dl[o] += b_dlt[o];
}

extern "C" void kernel_launch(void* const* d_in, const int* in_sizes, int n_in,
                              void* d_out, int out_size, void* d_ws, size_t ws_size,
                              hipStream_t stream) {
    const float* in    = (const float*)d_in[0];
    const float* w_sh  = (const float*)d_in[1];
    const float* b_sh  = (const float*)d_in[2];
    const float* w_cls = (const float*)d_in[3];
    const float* b_cls = (const float*)d_in[4];
    const float* w_dlt = (const float*)d_in[5];
    const float* b_dlt = (const float*)d_in[6];
    float* out = (float*)d_out;

    const size_t in_p_elems = (size_t)BATCH*HP*HP*CIN;   // 17,305,600
    const size_t wt_elems   = (size_t)9*CO*CIN;          // 1,179,648
    const size_t part_elems = (size_t)2*NPIX*18;         // 2,359,296
    const size_t need = (in_p_elems + wt_elems)*2 + part_elems*4;  // ~46.4 MB

    if (ws_size >= need) {
        unsigned short* in_p = (unsigned short*)d_ws;
        unsigned short* wt   = in_p + in_p_elems;
        float* part = (float*)(wt + wt_elems);
        hipFuncSetAttribute((const void*)k_main8,
                            hipFuncAttributeMaxDynamicSharedMemorySize, 163840);
        int padq = (int)(((size_t)BATCH*HP*HP*64 + 255)/256);
        k_pad_convert<<<padq, 256, 0, stream>>>(in, in_p);
        k_wt_convert<<<9*CO, 256, 0, stream>>>(w_sh, wt);
        k_main8<<<512, 512, 163840, stream>>>(in_p, wt, b_sh, w_cls, w_dlt, part);
        k_finalize_ws<<<(NPIX + 255)/256, 256, 0, stream>>>(part, out, b_cls, b_dlt);
    } else {
        hipMemsetAsync(d_out, 0, (size_t)out_size * sizeof(float), stream);
        k_main_fb<<<2048, 256, 0, stream>>>(in, w_sh, b_sh, w_cls, w_dlt, out);
        k_finalize<<<(NPIX + 255)/256, 256, 0, stream>>>(out, b_cls, b_dlt);
    }
}